// Round 1
// baseline (681.978 us; speedup 1.0000x reference)
//
#include <hip/hip_runtime.h>
#include <math.h>

// Problem constants (from reference): B=32, C=D=64, H=W=32
#define NPTS 32768      // B*H*W
#define KCB  1024       // num_embeddings
#define DIM  64         // embedding dim
#define HW   1024       // H*W
#define CHW  65536      // C*H*W
#define CHUNK 128       // codebook codes staged in LDS per pass (32 KB)
#define RWIN 12         // OT band radius: terms beyond this underflow to 0 in fp32 (proof: 20*12 - (4.5 + 20*5.02) = +47 margin below exp underflow)
#define WSZ  (2*RWIN+1)

__device__ __forceinline__ float block_sum(float v, float* scratch) {
  #pragma unroll
  for (int o = 32; o > 0; o >>= 1) v += __shfl_down(v, o, 64);
  int wid  = threadIdx.x >> 6;
  int lane = threadIdx.x & 63;
  __syncthreads();                 // protect scratch from previous use
  if (lane == 0) scratch[wid] = v;
  __syncthreads();
  float s = 0.f;
  int nw = blockDim.x >> 6;
  for (int w = 0; w < nw; ++w) s += scratch[w];
  return s;                        // same value in all threads
}

// K0: codebook row norms, zero hist + mse accumulator (ws re-poisoned every call)
__global__ __launch_bounds__(256) void k_init(const float* __restrict__ cb,
                                              float* __restrict__ cnorm,
                                              int* __restrict__ hist,
                                              float* __restrict__ msesum) {
  int k = blockIdx.x * 256 + threadIdx.x;
  if (k < KCB) {
    const float4* c4 = (const float4*)(cb + k * DIM);
    float s = 0.f;
    #pragma unroll
    for (int d = 0; d < DIM/4; ++d) {
      float4 v = c4[d];
      s = fmaf(v.x, v.x, s); s = fmaf(v.y, v.y, s);
      s = fmaf(v.z, v.z, s); s = fmaf(v.w, v.w, s);
    }
    cnorm[k] = s;
    hist[k] = 0;
  }
  if (k == 0) msesum[0] = 0.f;
}

// K1: per point -> argmin over codebook, hist count, quantized output, mse partial
__global__ __launch_bounds__(256) void k_main(const float* __restrict__ x,
                                              const float* __restrict__ cb,
                                              const float* __restrict__ cnorm,
                                              float* __restrict__ out,
                                              int* __restrict__ hist,
                                              float* __restrict__ msesum) {
  __shared__ float lc[CHUNK * DIM];   // 32 KB codebook chunk
  __shared__ float scratch[4];
  int n  = blockIdx.x * 256 + threadIdx.x;   // grid covers NPTS exactly
  int b  = n >> 10;
  int hw = n & 1023;
  const float* xp = x + b * CHW + hw;

  float xr[DIM];
  #pragma unroll
  for (int c = 0; c < DIM; ++c) xr[c] = xp[c * HW];   // coalesced across lanes per c
  float sumx = 0.f;
  #pragma unroll
  for (int c = 0; c < DIM; ++c) sumx = fmaf(xr[c], xr[c], sumx);

  float best = 3.4e38f;
  int bidx = 0;
  for (int k0 = 0; k0 < KCB; k0 += CHUNK) {
    __syncthreads();
    const float4* s4 = (const float4*)(cb + k0 * DIM);
    float4* d4 = (float4*)lc;
    #pragma unroll
    for (int t = 0; t < (CHUNK * DIM / 4) / 256; ++t)   // 8 float4 per thread
      d4[t * 256 + threadIdx.x] = s4[t * 256 + threadIdx.x];
    __syncthreads();
    for (int kk = 0; kk < CHUNK; ++kk) {
      const float4* c4 = (const float4*)(lc + kk * DIM);  // wave-uniform -> LDS broadcast
      float dot = 0.f;
      #pragma unroll
      for (int d = 0; d < DIM/4; ++d) {
        float4 v = c4[d];
        dot = fmaf(xr[4*d+0], v.x, dot);
        dot = fmaf(xr[4*d+1], v.y, dot);
        dot = fmaf(xr[4*d+2], v.z, dot);
        dot = fmaf(xr[4*d+3], v.w, dot);
      }
      // mimic reference fp32 rounding: (||x||^2 + ||c||^2) - 2*x.c
      float dist = (sumx + cnorm[k0 + kk]) - 2.0f * dot;
      if (dist < best) { best = dist; bidx = k0 + kk; }  // strict <: first-min tiebreak like np.argmin
    }
  }

  atomicAdd(&hist[bidx], 1);

  const float4* q4 = (const float4*)(cb + bidx * DIM);
  float* op = out + b * CHW + hw;
  float se = 0.f;
  #pragma unroll
  for (int d = 0; d < DIM/4; ++d) {
    float4 q = q4[d];
    float qq[4] = {q.x, q.y, q.z, q.w};
    #pragma unroll
    for (int j = 0; j < 4; ++j) {
      int c = 4*d + j;
      float diff = qq[j] - xr[c];       // = nq - x (stop-grad path)
      se += diff * diff;                // (clean_q - flat)^2
      op[c * HW] = xr[c] + diff;        // straight-through: x + (nq - x)
    }
  }
  float tot = block_sum(se, scratch);
  if (threadIdx.x == 0) atomicAdd(msesum, tot);
}

// K2: banded entropic-OT dual ascent (10 steps) + objective + loss/perplexity
__global__ __launch_bounds__(1024) void k_ot(const int* __restrict__ hist,
                                             const float* __restrict__ msesum,
                                             float* __restrict__ out) {
  __shared__ float s_src[KCB], s_lt[KCB], s_phi[KCB], s_lse[KCB];
  __shared__ float scratch[16];
  int i = threadIdx.x;
  float fi = (float)i;

  // Gaussian target + norm_prob (twice, as in reference)
  float zz = (fi - 511.5f) / (1024.0f / 6.0f);
  float t  = expf(-0.5f * zz * zz);
  float St = block_sum(t, scratch);
  float tgt0 = t / fmaxf(St, 1e-12f);
  float tgtc = fmaxf(tgt0, 1e-12f);
  float St2  = block_sum(tgtc, scratch);
  float tgtw = tgtc / St2;
  float ltw  = logf(fmaxf(tgtw, 1e-12f));
  s_lt[i] = ltw;

  // src weights: norm_prob(norm_prob(hard_hist))
  float h  = (float)hist[i] * (1.0f / 32768.0f);   // exact in fp32
  float m1 = fmaxf(h, 1e-12f);
  float S1 = block_sum(m1, scratch);
  float cw = m1 / S1;
  float m2 = fmaxf(cw, 1e-12f);
  float S2 = block_sum(m2, scratch);
  float srcw = m2 / S2;
  s_src[i] = srcw;
  s_phi[i] = 0.f;
  __syncthreads();

  for (int it = 0; it <= 10; ++it) {
    // Phase A: lse_i = logsumexp_j( log t_j + (phi_j - |i-j|)/eps ) over band
    float m = -3.0e38f;
    float vv[WSZ];
    #pragma unroll
    for (int q = 0; q < WSZ; ++q) {
      int j = i - RWIN + q;
      bool ok = (j >= 0) && (j < KCB);
      int jc = ok ? j : i;
      float a = s_lt[jc] + (s_phi[jc] - fabsf((float)(i - j))) * 20.0f;
      a = ok ? a : -3.0e38f;
      vv[q] = a;
      m = fmaxf(m, a);
    }
    float ssum = 0.f;
    #pragma unroll
    for (int q = 0; q < WSZ; ++q) ssum += expf(vv[q] - m);
    s_lse[i] = m + logf(ssum);
    __syncthreads();
    if (it == 10) break;   // 11th lse eval is for the final objective

    // Phase B (column j = i): grad_j = tgt_j - sum_i src_i * p_ij ; phi += 0.5*grad
    float basej = ltw + s_phi[i] * 20.0f;
    float cs = 0.f;
    #pragma unroll
    for (int q = 0; q < WSZ; ++q) {
      int r = i - RWIN + q;
      bool ok = (r >= 0) && (r < KCB);
      int rc = ok ? r : i;
      float a = basej - fabsf((float)(i - r)) * 20.0f;
      float term = s_src[rc] * expf(a - s_lse[rc]);
      cs += ok ? term : 0.f;
    }
    s_phi[i] += 0.5f * (tgtw - cs);
    __syncthreads();
  }

  // objective: sum_i src_i * (-eps*lse_i) + sum_j tgt_j * phi_j
  float term = srcw * (-0.05f * s_lse[i]) + tgtw * s_phi[i];
  float ot   = block_sum(term, scratch);

  // perplexity from hard hist
  float pterm = h * logf(h + 1e-10f);
  float ent   = block_sum(pterm, scratch);

  if (i == 0) {
    float mse = msesum[0] * (1.0f / 2097152.0f);   // N*D
    out[2097152] = 1.25f * mse + ot;               // codebook + 0.25*commit + 1.0*ot
    out[2097153] = expf(-ent);
  }
}

extern "C" void kernel_launch(void* const* d_in, const int* in_sizes, int n_in,
                              void* d_out, int out_size, void* d_ws, size_t ws_size,
                              hipStream_t stream) {
  const float* x  = (const float*)d_in[0];   // [32,64,32,32]
  const float* cb = (const float*)d_in[1];   // [1024,64]
  float* out = (float*)d_out;                // quantized(2097152) | loss | perplexity

  float* cnorm  = (float*)d_ws;
  int*   hist   = (int*)((char*)d_ws + 4096);
  float* msesum = (float*)((char*)d_ws + 8192);

  k_init<<<4, 256, 0, stream>>>(cb, cnorm, hist, msesum);
  k_main<<<NPTS / 256, 256, 0, stream>>>(x, cb, cnorm, out, hist, msesum);
  k_ot<<<1, 1024, 0, stream>>>(hist, msesum, out);
}

// Round 2
// 208.639 us; speedup vs baseline: 3.2687x; 3.2687x over previous
//
#include <hip/hip_runtime.h>
#include <math.h>

// Problem constants: B=32, C=D=64, H=W=32
#define NPTS 32768      // B*H*W
#define KCB  1024
#define DIM  64
#define HW   1024
#define CHW  65536
#define PT   128        // points per block tile
#define CT   128        // codes per block tile
#define RWIN 12         // OT band radius: beyond this exp() underflows to exactly 0 in fp32
#define WSZ  (2*RWIN+1)

__device__ __forceinline__ float block_sum(float v, float* scratch) {
  #pragma unroll
  for (int o = 32; o > 0; o >>= 1) v += __shfl_down(v, o, 64);
  int wid  = threadIdx.x >> 6;
  int lane = threadIdx.x & 63;
  __syncthreads();
  if (lane == 0) scratch[wid] = v;
  __syncthreads();
  float s = 0.f;
  int nw = blockDim.x >> 6;
  for (int w = 0; w < nw; ++w) s += scratch[w];
  return s;
}

// K0: codebook row norms (same fma chain order as k-loop dots), zero hist/mse
__global__ __launch_bounds__(256) void k_init(const float* __restrict__ cb,
                                              float* __restrict__ cnorm,
                                              int* __restrict__ hist,
                                              float* __restrict__ msesum) {
  int k = blockIdx.x * 256 + threadIdx.x;
  if (k < KCB) {
    const float4* c4 = (const float4*)(cb + k * DIM);
    float s = 0.f;
    #pragma unroll
    for (int d = 0; d < DIM/4; ++d) {
      float4 v = c4[d];
      s = fmaf(v.x, v.x, s); s = fmaf(v.y, v.y, s);
      s = fmaf(v.z, v.z, s); s = fmaf(v.w, v.w, s);
    }
    cnorm[k] = s;
    hist[k] = 0;
  }
  if (k == 0) msesum[0] = 0.f;
}

// K1: register-tiled distance GEMM + per-(pt,codetile) argmin partial.
// Block: 128 pts x 128 codes. Thread: 8x8. launch_bounds(256,2): 2 blocks/CU,
// 256-VGPR budget so acc[8][8]+operands stay in registers (R1 spilled at 60 VGPR).
__global__ __launch_bounds__(256, 2) void k_dist(const float* __restrict__ x,
                                                 const float* __restrict__ cb,
                                                 const float* __restrict__ cnorm,
                                                 unsigned long long* __restrict__ partial) {
  __shared__ float4 lp[DIM][PT/4];   // points, dim-major, 32 KB
  __shared__ float4 lc[DIM][CT/4];   // codes,  dim-major, 32 KB, float4 j stored at (j>>1)+(j&1)*16
  int tid = threadIdx.x;
  int t   = blockIdx.x;              // point tile
  int ct  = blockIdx.y;              // code tile
  int k0  = ct * CT;
  int n0  = t * PT;
  int b   = n0 >> 10;                // 8 pt-tiles per batch image -> single b per tile
  int hw0 = n0 & 1023;

  // stage points: [d][p] from x[b][c][hw0+p]; coalesced 512B rows
  {
    const float* xb = x + b * CHW + hw0;
    int crow = tid >> 5, p4 = tid & 31;
    #pragma unroll
    for (int i = 0; i < 8; ++i) {
      int c = i * 8 + crow;
      lp[c][p4] = *(const float4*)(xb + c * HW + p4 * 4);
    }
  }
  // stage codes transposed: two threads per code row; deinterleave float4 groups
  // so k-loop reads (g=tx | g=16+tx) hit all 8 bank-quads -> 2-way (free)
  {
    int cc   = tid >> 1;
    int half = tid & 1;
    const float4* row = (const float4*)(cb + (k0 + cc) * DIM) + half * 8;
    int j = cc >> 2;
    int g = (j >> 1) + (j & 1) * 16;
    int e = cc & 3;
    float* lcf = (float*)&lc[0][0];
    #pragma unroll
    for (int i = 0; i < 8; ++i) {
      float4 v = row[i];
      int d = half * 32 + i * 4;
      lcf[(d + 0) * CT + g * 4 + e] = v.x;
      lcf[(d + 1) * CT + g * 4 + e] = v.y;
      lcf[(d + 2) * CT + g * 4 + e] = v.z;
      lcf[(d + 3) * CT + g * 4 + e] = v.w;
    }
  }
  __syncthreads();

  int tx = tid & 15, ty = tid >> 4;
  float acc[8][8];
  float sx[8];
  #pragma unroll
  for (int pp = 0; pp < 8; ++pp) {
    sx[pp] = 0.f;
    #pragma unroll
    for (int cc = 0; cc < 8; ++cc) acc[pp][cc] = 0.f;
  }

  #pragma unroll 8
  for (int d = 0; d < DIM; ++d) {
    float4 a0 = lp[d][ty * 2];
    float4 a1 = lp[d][ty * 2 + 1];
    float4 b0 = lc[d][tx];          // codes tx*8..tx*8+3 (deinterleaved slot tx)
    float4 b1 = lc[d][16 + tx];     // codes tx*8+4..tx*8+7
    float av[8] = {a0.x, a0.y, a0.z, a0.w, a1.x, a1.y, a1.z, a1.w};
    float bv[8] = {b0.x, b0.y, b0.z, b0.w, b1.x, b1.y, b1.z, b1.w};
    #pragma unroll
    for (int pp = 0; pp < 8; ++pp) {
      sx[pp] = fmaf(av[pp], av[pp], sx[pp]);
      #pragma unroll
      for (int cc = 0; cc < 8; ++cc)
        acc[pp][cc] = fmaf(av[pp], bv[cc], acc[pp][cc]);
    }
  }

  float cn[8];
  #pragma unroll
  for (int cc = 0; cc < 8; ++cc) cn[cc] = cnorm[k0 + tx * 8 + cc];

  #pragma unroll
  for (int pp = 0; pp < 8; ++pp) {
    float best = 3.4e38f; int bidx = 0;
    #pragma unroll
    for (int cc = 0; cc < 8; ++cc) {
      // mimic reference fp32 rounding: (||x||^2 + ||c||^2) - 2*x.c
      float dist = (sx[pp] + cn[cc]) - 2.0f * acc[pp][cc];
      if (dist < best) { best = dist; bidx = k0 + tx * 8 + cc; }  // strict <: first-min
    }
    // pack (dist,idx): min over packed = min dist, tie -> min idx (np.argmin order)
    unsigned long long pk = ((unsigned long long)__float_as_uint(best) << 32) | (unsigned)bidx;
    #pragma unroll
    for (int m = 1; m < 16; m <<= 1) {
      unsigned long long o = __shfl_xor(pk, m, 64);
      pk = (o < pk) ? o : pk;
    }
    if (tx == 0) partial[(unsigned)(n0 + ty * 8 + pp) * 8 + ct] = pk;
  }
}

// K2: combine 8 code-tile partials per point; hist, mse, straight-through write
__global__ __launch_bounds__(256) void k_fin(const float* __restrict__ x,
                                             const float* __restrict__ cb,
                                             const unsigned long long* __restrict__ partial,
                                             float* __restrict__ out,
                                             int* __restrict__ hist,
                                             float* __restrict__ msesum) {
  __shared__ float scratch[4];
  int n = blockIdx.x * 256 + threadIdx.x;
  const unsigned long long* pp = partial + (unsigned)n * 8;
  unsigned long long best = pp[0];
  #pragma unroll
  for (int j = 1; j < 8; ++j) {
    unsigned long long u = pp[j];
    best = (u < best) ? u : best;
  }
  int bidx = (int)(best & 0xffffffffull);
  atomicAdd(&hist[bidx], 1);

  int b = n >> 10, hw = n & 1023;
  const float* xp = x + b * CHW + hw;
  float* op = out + b * CHW + hw;
  const float4* q4 = (const float4*)(cb + bidx * DIM);
  float se = 0.f;
  #pragma unroll
  for (int d = 0; d < DIM/4; ++d) {
    float4 q = q4[d];
    float qq[4] = {q.x, q.y, q.z, q.w};
    #pragma unroll
    for (int j = 0; j < 4; ++j) {
      int c = 4 * d + j;
      float xv = xp[c * HW];
      float diff = qq[j] - xv;       // nq - x
      se += diff * diff;             // (clean_q - flat)^2 == commit mse
      op[c * HW] = xv + diff;        // x + stop_grad(nq - x), same rounding as ref
    }
  }
  float tot = block_sum(se, scratch);
  if (threadIdx.x == 0) atomicAdd(msesum, tot);
}

// K3: banded entropic-OT dual ascent (10 steps) + objective + loss/perplexity
__global__ __launch_bounds__(1024) void k_ot(const int* __restrict__ hist,
                                             const float* __restrict__ msesum,
                                             float* __restrict__ out) {
  __shared__ float s_src[KCB], s_lt[KCB], s_phi[KCB], s_lse[KCB];
  __shared__ float scratch[16];
  int i = threadIdx.x;
  float fi = (float)i;

  float zz = (fi - 511.5f) / (1024.0f / 6.0f);
  float t  = expf(-0.5f * zz * zz);
  float St = block_sum(t, scratch);
  float tgt0 = t / fmaxf(St, 1e-12f);
  float tgtc = fmaxf(tgt0, 1e-12f);
  float St2  = block_sum(tgtc, scratch);
  float tgtw = tgtc / St2;
  float ltw  = logf(fmaxf(tgtw, 1e-12f));
  s_lt[i] = ltw;

  float h  = (float)hist[i] * (1.0f / 32768.0f);
  float m1 = fmaxf(h, 1e-12f);
  float S1 = block_sum(m1, scratch);
  float cw = m1 / S1;
  float m2 = fmaxf(cw, 1e-12f);
  float S2 = block_sum(m2, scratch);
  float srcw = m2 / S2;
  s_src[i] = srcw;
  s_phi[i] = 0.f;
  __syncthreads();

  for (int it = 0; it <= 10; ++it) {
    float m = -3.0e38f;
    float vv[WSZ];
    #pragma unroll
    for (int q = 0; q < WSZ; ++q) {
      int j = i - RWIN + q;
      bool ok = (j >= 0) && (j < KCB);
      int jc = ok ? j : i;
      float a = s_lt[jc] + (s_phi[jc] - fabsf((float)(i - j))) * 20.0f;
      a = ok ? a : -3.0e38f;
      vv[q] = a;
      m = fmaxf(m, a);
    }
    float ssum = 0.f;
    #pragma unroll
    for (int q = 0; q < WSZ; ++q) ssum += expf(vv[q] - m);
    s_lse[i] = m + logf(ssum);
    __syncthreads();
    if (it == 10) break;

    float basej = ltw + s_phi[i] * 20.0f;
    float cs = 0.f;
    #pragma unroll
    for (int q = 0; q < WSZ; ++q) {
      int r = i - RWIN + q;
      bool ok = (r >= 0) && (r < KCB);
      int rc = ok ? r : i;
      float a = basej - fabsf((float)(i - r)) * 20.0f;
      float term = s_src[rc] * expf(a - s_lse[rc]);
      cs += ok ? term : 0.f;
    }
    s_phi[i] += 0.5f * (tgtw - cs);
    __syncthreads();
  }

  float term = srcw * (-0.05f * s_lse[i]) + tgtw * s_phi[i];
  float ot   = block_sum(term, scratch);
  float pterm = h * logf(h + 1e-10f);
  float ent   = block_sum(pterm, scratch);

  if (i == 0) {
    float mse = msesum[0] * (1.0f / 2097152.0f);
    out[2097152] = 1.25f * mse + ot;
    out[2097153] = expf(-ent);
  }
}

extern "C" void kernel_launch(void* const* d_in, const int* in_sizes, int n_in,
                              void* d_out, int out_size, void* d_ws, size_t ws_size,
                              hipStream_t stream) {
  const float* x  = (const float*)d_in[0];   // [32,64,32,32]
  const float* cb = (const float*)d_in[1];   // [1024,64]
  float* out = (float*)d_out;

  float* cnorm  = (float*)d_ws;
  int*   hist   = (int*)((char*)d_ws + 4096);
  float* msesum = (float*)((char*)d_ws + 8192);
  unsigned long long* partial = (unsigned long long*)((char*)d_ws + 16384);  // 32768*8*8B = 2 MB

  k_init<<<4, 256, 0, stream>>>(cb, cnorm, hist, msesum);
  k_dist<<<dim3(NPTS / PT, KCB / CT), 256, 0, stream>>>(x, cb, cnorm, partial);
  k_fin<<<NPTS / 256, 256, 0, stream>>>(x, cb, partial, out, hist, msesum);
  k_ot<<<1, 1024, 0, stream>>>(hist, msesum, out);
}

// Round 3
// 152.547 us; speedup vs baseline: 4.4706x; 1.3677x over previous
//
#include <hip/hip_runtime.h>
#include <math.h>

// Problem constants: B=32, C=D=64, H=W=32
#define NPTS 32768      // B*H*W
#define KCB  1024
#define DIM  64
#define HW   1024
#define CHW  65536
#define PT   128        // points per block tile (k_dist)
#define CT   128        // codes per block tile (k_dist)
#define RWIN 2          // OT band radius; d>=3 terms are <= e^-57 relative (see theory)
#define WSZ  (2*RWIN+1)
#define OTB  192        // k_otp block width: 64 owned + 64 halo each side (cone = 42 <= 64)

__device__ __forceinline__ float block_sum(float v, float* scratch) {
  #pragma unroll
  for (int o = 32; o > 0; o >>= 1) v += __shfl_down(v, o, 64);
  int wid  = threadIdx.x >> 6;
  int lane = threadIdx.x & 63;
  __syncthreads();
  if (lane == 0) scratch[wid] = v;
  __syncthreads();
  float s = 0.f;
  int nw = blockDim.x >> 6;
  for (int w = 0; w < nw; ++w) s += scratch[w];
  return s;
}

// K0: codebook row norms (same fma chain order as k-loop dots), zero hist/mse
__global__ __launch_bounds__(256) void k_init(const float* __restrict__ cb,
                                              float* __restrict__ cnorm,
                                              int* __restrict__ hist,
                                              float* __restrict__ msesum) {
  int k = blockIdx.x * 256 + threadIdx.x;
  if (k < KCB) {
    const float4* c4 = (const float4*)(cb + k * DIM);
    float s = 0.f;
    #pragma unroll
    for (int d = 0; d < DIM/4; ++d) {
      float4 v = c4[d];
      s = fmaf(v.x, v.x, s); s = fmaf(v.y, v.y, s);
      s = fmaf(v.z, v.z, s); s = fmaf(v.w, v.w, s);
    }
    cnorm[k] = s;
    hist[k] = 0;
  }
  if (k == 0) msesum[0] = 0.f;
}

// K1: register-tiled distance GEMM + per-(pt,codetile) argmin partial. (unchanged from R2)
__global__ __launch_bounds__(256, 2) void k_dist(const float* __restrict__ x,
                                                 const float* __restrict__ cb,
                                                 const float* __restrict__ cnorm,
                                                 unsigned long long* __restrict__ partial) {
  __shared__ float4 lp[DIM][PT/4];   // points, dim-major, 32 KB
  __shared__ float4 lc[DIM][CT/4];   // codes,  dim-major, 32 KB, deinterleaved float4 slots
  int tid = threadIdx.x;
  int t   = blockIdx.x;
  int ct  = blockIdx.y;
  int k0  = ct * CT;
  int n0  = t * PT;
  int b   = n0 >> 10;
  int hw0 = n0 & 1023;

  {
    const float* xb = x + b * CHW + hw0;
    int crow = tid >> 5, p4 = tid & 31;
    #pragma unroll
    for (int i = 0; i < 8; ++i) {
      int c = i * 8 + crow;
      lp[c][p4] = *(const float4*)(xb + c * HW + p4 * 4);
    }
  }
  {
    int cc   = tid >> 1;
    int half = tid & 1;
    const float4* row = (const float4*)(cb + (k0 + cc) * DIM) + half * 8;
    int j = cc >> 2;
    int g = (j >> 1) + (j & 1) * 16;
    int e = cc & 3;
    float* lcf = (float*)&lc[0][0];
    #pragma unroll
    for (int i = 0; i < 8; ++i) {
      float4 v = row[i];
      int d = half * 32 + i * 4;
      lcf[(d + 0) * CT + g * 4 + e] = v.x;
      lcf[(d + 1) * CT + g * 4 + e] = v.y;
      lcf[(d + 2) * CT + g * 4 + e] = v.z;
      lcf[(d + 3) * CT + g * 4 + e] = v.w;
    }
  }
  __syncthreads();

  int tx = tid & 15, ty = tid >> 4;
  float acc[8][8];
  float sx[8];
  #pragma unroll
  for (int pp = 0; pp < 8; ++pp) {
    sx[pp] = 0.f;
    #pragma unroll
    for (int cc = 0; cc < 8; ++cc) acc[pp][cc] = 0.f;
  }

  #pragma unroll 8
  for (int d = 0; d < DIM; ++d) {
    float4 a0 = lp[d][ty * 2];
    float4 a1 = lp[d][ty * 2 + 1];
    float4 b0 = lc[d][tx];
    float4 b1 = lc[d][16 + tx];
    float av[8] = {a0.x, a0.y, a0.z, a0.w, a1.x, a1.y, a1.z, a1.w};
    float bv[8] = {b0.x, b0.y, b0.z, b0.w, b1.x, b1.y, b1.z, b1.w};
    #pragma unroll
    for (int pp = 0; pp < 8; ++pp) {
      sx[pp] = fmaf(av[pp], av[pp], sx[pp]);
      #pragma unroll
      for (int cc = 0; cc < 8; ++cc)
        acc[pp][cc] = fmaf(av[pp], bv[cc], acc[pp][cc]);
    }
  }

  float cn[8];
  #pragma unroll
  for (int cc = 0; cc < 8; ++cc) cn[cc] = cnorm[k0 + tx * 8 + cc];

  #pragma unroll
  for (int pp = 0; pp < 8; ++pp) {
    float best = 3.4e38f; int bidx = 0;
    #pragma unroll
    for (int cc = 0; cc < 8; ++cc) {
      float dist = (sx[pp] + cn[cc]) - 2.0f * acc[pp][cc];
      if (dist < best) { best = dist; bidx = k0 + tx * 8 + cc; }
    }
    unsigned long long pk = ((unsigned long long)__float_as_uint(best) << 32) | (unsigned)bidx;
    #pragma unroll
    for (int m = 1; m < 16; m <<= 1) {
      unsigned long long o = __shfl_xor(pk, m, 64);
      pk = (o < pk) ? o : pk;
    }
    if (tx == 0) partial[(unsigned)(n0 + ty * 8 + pp) * 8 + ct] = pk;
  }
}

// K2: combine code-tile partials; hist, mse, straight-through write (unchanged from R2)
__global__ __launch_bounds__(256) void k_fin(const float* __restrict__ x,
                                             const float* __restrict__ cb,
                                             const unsigned long long* __restrict__ partial,
                                             float* __restrict__ out,
                                             int* __restrict__ hist,
                                             float* __restrict__ msesum) {
  __shared__ float scratch[4];
  int n = blockIdx.x * 256 + threadIdx.x;
  const unsigned long long* pp = partial + (unsigned)n * 8;
  unsigned long long best = pp[0];
  #pragma unroll
  for (int j = 1; j < 8; ++j) {
    unsigned long long u = pp[j];
    best = (u < best) ? u : best;
  }
  int bidx = (int)(best & 0xffffffffull);
  atomicAdd(&hist[bidx], 1);

  int b = n >> 10, hw = n & 1023;
  const float* xp = x + b * CHW + hw;
  float* op = out + b * CHW + hw;
  const float4* q4 = (const float4*)(cb + bidx * DIM);
  float se = 0.f;
  #pragma unroll
  for (int d = 0; d < DIM/4; ++d) {
    float4 q = q4[d];
    float qq[4] = {q.x, q.y, q.z, q.w};
    #pragma unroll
    for (int j = 0; j < 4; ++j) {
      int c = 4 * d + j;
      float xv = xp[c * HW];
      float diff = qq[j] - xv;
      se += diff * diff;
      op[c * HW] = xv + diff;
    }
  }
  float tot = block_sum(se, scratch);
  if (threadIdx.x == 0) atomicAdd(msesum, tot);
}

// K3: global normalizations + entropy (1 block x 1024; same summation order as R2)
__global__ __launch_bounds__(1024) void k_prep(const int* __restrict__ hist,
                                               float* __restrict__ srcw_g,
                                               float* __restrict__ ltw_g,
                                               float* __restrict__ tgtw_g,
                                               float* __restrict__ scal) {  // scal[0]=otsum, scal[1]=ent
  __shared__ float scratch[16];
  int i = threadIdx.x;
  float fi = (float)i;

  float zz = (fi - 511.5f) / (1024.0f / 6.0f);
  float t  = expf(-0.5f * zz * zz);
  float St = block_sum(t, scratch);
  float tgt0 = t / fmaxf(St, 1e-12f);
  float tgtc = fmaxf(tgt0, 1e-12f);
  float St2  = block_sum(tgtc, scratch);
  float tgtw = tgtc / St2;
  float ltw  = logf(fmaxf(tgtw, 1e-12f));

  float h  = (float)hist[i] * (1.0f / 32768.0f);
  float m1 = fmaxf(h, 1e-12f);
  float S1 = block_sum(m1, scratch);
  float cw = m1 / S1;
  float m2 = fmaxf(cw, 1e-12f);
  float S2 = block_sum(m2, scratch);
  float srcw = m2 / S2;

  srcw_g[i] = srcw;
  ltw_g[i]  = ltw;
  tgtw_g[i] = tgtw;

  float pterm = h * logf(h + 1e-10f);
  float ent   = block_sum(pterm, scratch);
  if (i == 0) { scal[0] = 0.f; scal[1] = ent; }
}

// K4: banded OT dual ascent, cone-replicated: 16 blocks x 192 threads, no inter-block sync.
// Block bk owns global indices [bk*64, bk*64+64); thread li covers gi = bk*64-64+li.
// Correctness cone: per iteration region shrinks 2*RWIN=4/side; 10 iters + final A = 42 <= 64 halo.
__global__ __launch_bounds__(OTB) void k_otp(const float* __restrict__ srcw_g,
                                             const float* __restrict__ ltw_g,
                                             const float* __restrict__ tgtw_g,
                                             float* __restrict__ scal) {
  __shared__ float s_lt[OTB + 2*RWIN], s_src[OTB + 2*RWIN],
                   s_phi[OTB + 2*RWIN], s_lse[OTB + 2*RWIN];
  int li = threadIdx.x;
  int gi = blockIdx.x * 64 - 64 + li;
  bool valid = (gi >= 0) && (gi < KCB);

  // invalid lanes: lt=-100, src=0, tgt=0 -> provably inert (every exp arg <= 0, contributions
  // flush below fp32 eps of row max); pads likewise.
  float lt  = valid ? ltw_g[gi]  : -100.f;
  float src = valid ? srcw_g[gi] : 0.f;
  float tgt = valid ? tgtw_g[gi] : 0.f;
  float phi = 0.f;
  int sl = li + RWIN;
  s_lt[sl] = lt; s_src[sl] = src; s_phi[sl] = 0.f; s_lse[sl] = 0.f;
  if (li < RWIN)        { s_lt[li] = -100.f; s_src[li] = 0.f; s_phi[li] = 0.f; s_lse[li] = 0.f; }
  if (li >= OTB - RWIN) { int p = li + 2*RWIN; s_lt[p] = -100.f; s_src[p] = 0.f; s_phi[p] = 0.f; s_lse[p] = 0.f; }
  __syncthreads();

  float lse = 0.f;
  for (int it = 0; it <= 10; ++it) {
    // Phase A: lse_i = logsumexp_j in band of [lt_j + 20*(phi_j - |i-j|)]
    float m = -3.0e38f;
    float vv[WSZ];
    #pragma unroll
    for (int q = 0; q < WSZ; ++q) {
      float a = s_lt[li + q] + (s_phi[li + q] - fabsf((float)(q - RWIN))) * 20.0f;
      vv[q] = a;
      m = fmaxf(m, a);
    }
    float ssum = 0.f;
    #pragma unroll
    for (int q = 0; q < WSZ; ++q) ssum += expf(vv[q] - m);
    lse = m + logf(ssum);
    s_lse[sl] = lse;
    __syncthreads();
    if (it == 10) break;

    // Phase B: cs_j = sum_r src_r * exp(lt_j + 20*phi_j - 20|j-r| - lse_r); phi_j += 0.5*(tgt_j - cs_j)
    float basej = lt + phi * 20.0f;
    float cs = 0.f;
    #pragma unroll
    for (int q = 0; q < WSZ; ++q) {
      float a = basej - fabsf((float)(q - RWIN)) * 20.0f;
      cs += s_src[li + q] * expf(a - s_lse[li + q]);
    }
    phi += 0.5f * (tgt - cs);
    s_phi[sl] = phi;
    __syncthreads();
  }

  // objective partial over owned 64 (li in [64,128) == wave 1; all valid)
  if (li >= 64 && li < 128) {
    float term = src * (-0.05f * lse) + tgt * phi;
    #pragma unroll
    for (int o = 32; o > 0; o >>= 1) term += __shfl_down(term, o, 64);
    if (li == 64) atomicAdd(&scal[0], term);
  }
}

// K5: final scalar combine
__global__ __launch_bounds__(64) void k_last(const float* __restrict__ msesum,
                                             const float* __restrict__ scal,
                                             float* __restrict__ out) {
  if (threadIdx.x == 0) {
    float mse = msesum[0] * (1.0f / 2097152.0f);   // N*D
    out[2097152] = 1.25f * mse + scal[0];          // codebook + 0.25*commit + ot
    out[2097153] = expf(-scal[1]);                 // perplexity
  }
}

extern "C" void kernel_launch(void* const* d_in, const int* in_sizes, int n_in,
                              void* d_out, int out_size, void* d_ws, size_t ws_size,
                              hipStream_t stream) {
  const float* x  = (const float*)d_in[0];   // [32,64,32,32]
  const float* cb = (const float*)d_in[1];   // [1024,64]
  float* out = (float*)d_out;

  float* cnorm  = (float*)d_ws;                              // 4 KB
  int*   hist   = (int*)((char*)d_ws + 4096);                // 4 KB
  float* msesum = (float*)((char*)d_ws + 8192);              // 4 B
  float* scal   = (float*)((char*)d_ws + 8192 + 256);        // otsum, ent
  float* srcw_g = (float*)((char*)d_ws + 12288);             // 4 KB
  float* ltw_g  = (float*)((char*)d_ws + 16384);             // 4 KB
  float* tgtw_g = (float*)((char*)d_ws + 20480);             // 4 KB
  unsigned long long* partial = (unsigned long long*)((char*)d_ws + 32768);  // 2 MB

  k_init<<<4, 256, 0, stream>>>(cb, cnorm, hist, msesum);
  k_dist<<<dim3(NPTS / PT, KCB / CT), 256, 0, stream>>>(x, cb, cnorm, partial);
  k_fin<<<NPTS / 256, 256, 0, stream>>>(x, cb, partial, out, hist, msesum);
  k_prep<<<1, 1024, 0, stream>>>(hist, srcw_g, ltw_g, tgtw_g, scal);
  k_otp<<<KCB / 64, OTB, 0, stream>>>(srcw_g, ltw_g, tgtw_g, scal);
  k_last<<<1, 64, 0, stream>>>(msesum, scal, out);
}